// Round 1
// baseline (551.837 us; speedup 1.0000x reference)
//
#include <hip/hip_runtime.h>

// SlideMean_Norm: out[b,0,t,f] = x[b,0,t,f] - mean(x[b,0,s:e,f]),
//   s = max(t-150, 0), e = min(t+150, T-1) (end-exclusive).
// Memory-bound streaming kernel: one thread per (column, t-chunk),
// running sliding-window sum in a register.

constexpr int B    = 32;
constexpr int T    = 16000;
constexpr int F    = 80;
constexpr int HALF = 150;        // WIN_LEN / 2
constexpr int CL   = 250;        // chunk length along t
constexpr int NCHUNK = T / CL;   // 64
constexpr int NCOL   = B * F;    // 2560 (multiple of 64 -> waves never split across chunks)
constexpr int NTHREADS = NCOL * NCHUNK;  // 163840

__global__ __launch_bounds__(256) void slide_mean_norm(const float* __restrict__ x,
                                                       float* __restrict__ out) {
    int tid   = blockIdx.x * 256 + threadIdx.x;
    int col   = tid % NCOL;       // consecutive lanes -> consecutive f (coalesced)
    int chunk = tid / NCOL;       // wave-uniform
    int b = col / F;
    int f = col % F;

    const float* xp = x   + (size_t)b * T * F + f;
    float*       op = out + (size_t)b * T * F + f;

    int t0 = chunk * CL;
    int s0 = t0 - HALF; if (s0 < 0) s0 = 0;
    int e0 = t0 + HALF; if (e0 > T - 1) e0 = T - 1;

    // Warm-up: W = sum over x[s0 .. e0)   (two accumulators for ILP)
    float w0 = 0.f, w1 = 0.f;
    int t = s0;
    for (; t + 1 < e0; t += 2) {
        w0 += xp[(size_t)t * F];
        w1 += xp[(size_t)(t + 1) * F];
    }
    if (t < e0) w0 += xp[(size_t)t * F];
    float W = w0 + w1;

    int tend = t0 + CL;
    for (int i = t0; i < tend; ++i) {
        int s = i - HALF; if (s < 0) s = 0;
        int e = i + HALF; if (e > T - 1) e = T - 1;
        float inv = 1.0f / (float)(e - s);      // wave-uniform
        float xi = xp[(size_t)i * F];
        op[(size_t)i * F] = xi - W * inv;
        // advance window for i+1
        if (i + HALF < T - 1) W += xp[(size_t)(i + HALF) * F];  // e grows
        if (i >= HALF)        W -= xp[(size_t)(i - HALF) * F];  // s grows
    }
}

extern "C" void kernel_launch(void* const* d_in, const int* in_sizes, int n_in,
                              void* d_out, int out_size, void* d_ws, size_t ws_size,
                              hipStream_t stream) {
    const float* x = (const float*)d_in[0];
    float* out = (float*)d_out;
    slide_mean_norm<<<dim3(NTHREADS / 256), dim3(256), 0, stream>>>(x, out);
}

// Round 2
// 530.408 us; speedup vs baseline: 1.0404x; 1.0404x over previous
//
#include <hip/hip_runtime.h>

// SlideMean_Norm: out[b,0,t,f] = x[b,0,t,f] - mean(x[b,0,s:e,f]),
//   s = max(t-150, 0), e = min(t+150, T-1) (end-exclusive).
// Latency-optimized streaming kernel: float2 columns, batched unrolled loads
// for deep MLP, running sliding-window sum in registers.

constexpr int B    = 32;
constexpr int T    = 16000;
constexpr int F    = 80;
constexpr int HALF = 150;          // WIN_LEN / 2
constexpr int CL   = 250;          // chunk length along t
constexpr int NCHUNK = T / CL;     // 64
constexpr int RS   = F / 2;        // row stride in float2 units = 40
constexpr int NCOL2 = B * F / 2;   // 1280 float2-columns (multiple of 64)
constexpr int NTHREADS = NCOL2 * NCHUNK;  // 81920
constexpr int BLOCK = 64;

__global__ __launch_bounds__(BLOCK) void slide_mean_norm(const float2* __restrict__ x,
                                                         float2* __restrict__ out) {
    int tid   = blockIdx.x * BLOCK + threadIdx.x;
    int col2  = tid % NCOL2;        // consecutive lanes -> consecutive float2 (coalesced)
    int chunk = tid / NCOL2;        // wave-uniform
    int b  = col2 / RS;
    int f2 = col2 % RS;

    const float2* xp = x   + (size_t)b * T * RS + f2;
    float2*       op = out + (size_t)b * T * RS + f2;

    int t0 = chunk * CL;
    float sx = 0.f, sy = 0.f;

    bool interior = (t0 >= HALF) && (t0 + CL - 1 + HALF <= T - 1);

    if (interior) {
        // ---- warm-up: exactly 300 rows [t0-150, t0+150), batches of 10 loads ----
        const float2* p = xp + (size_t)(t0 - HALF) * RS;
        #pragma unroll 1
        for (int k = 0; k < 2 * HALF; k += 10) {
            float2 v[10];
            #pragma unroll
            for (int j = 0; j < 10; ++j) v[j] = p[(k + j) * RS];
            #pragma unroll
            for (int j = 0; j < 10; ++j) { sx += v[j].x; sy += v[j].y; }
        }
        // ---- main: branchless, count == 300, 5 iters per waitcnt round ----
        const float inv = 1.0f / (2.0f * HALF);
        #pragma unroll 1
        for (int i = t0; i < t0 + CL; i += 5) {
            float2 c[5], ld[5], tr[5];
            #pragma unroll
            for (int j = 0; j < 5; ++j) {
                c[j]  = xp[(i + j) * RS];
                ld[j] = xp[(i + j + HALF) * RS];
                tr[j] = xp[(i + j - HALF) * RS];
            }
            #pragma unroll
            for (int j = 0; j < 5; ++j) {
                float ox = c[j].x - sx * inv;
                float oy = c[j].y - sy * inv;
                sx += ld[j].x - tr[j].x;
                sy += ld[j].y - tr[j].y;
                op[(i + j) * RS] = make_float2(ox, oy);
            }
        }
    } else {
        // ---- edge chunks (0 and 63): guarded path, wave-uniform branches ----
        int s0 = t0 - HALF; if (s0 < 0) s0 = 0;
        int e0 = t0 + HALF; if (e0 > T - 1) e0 = T - 1;
        #pragma unroll 1
        for (int t = s0; t < e0; ++t) {
            float2 v = xp[(size_t)t * RS];
            sx += v.x; sy += v.y;
        }
        #pragma unroll 1
        for (int i = t0; i < t0 + CL; ++i) {
            int s = i - HALF; if (s < 0) s = 0;
            int e = i + HALF; if (e > T - 1) e = T - 1;
            float inv = 1.0f / (float)(e - s);
            float2 c = xp[(size_t)i * RS];
            op[(size_t)i * RS] = make_float2(c.x - sx * inv, c.y - sy * inv);
            if (i + HALF < T - 1) { float2 v = xp[(size_t)(i + HALF) * RS]; sx += v.x; sy += v.y; }
            if (i >= HALF)        { float2 v = xp[(size_t)(i - HALF) * RS]; sx -= v.x; sy -= v.y; }
        }
    }
}

extern "C" void kernel_launch(void* const* d_in, const int* in_sizes, int n_in,
                              void* d_out, int out_size, void* d_ws, size_t ws_size,
                              hipStream_t stream) {
    const float2* x = (const float2*)d_in[0];
    float2* out = (float2*)d_out;
    slide_mean_norm<<<dim3(NTHREADS / BLOCK), dim3(BLOCK), 0, stream>>>(x, out);
}